// Round 5
// baseline (209.044 us; speedup 1.0000x reference)
//
#include <hip/hip_runtime.h>
#include <hip/hip_bf16.h>

// Dims fixed by the reference
#define BB 8
#define NN 2048
#define DF 256
#define HH 64

using bf16x8 = __attribute__((ext_vector_type(8))) short;
using f32x4  = __attribute__((ext_vector_type(4))) float;
typedef unsigned short u16;

static __device__ __forceinline__ short bf_hi_bits(float v, float* hi_f) {
    __hip_bfloat16 h = __float2bfloat16(v);
    *hi_f = __bfloat162float(h);
    return __builtin_bit_cast(short, h);
}

// ---------------------------------------------------------------------------
// Kernel 0: pre-split W (fp32) into MFMA B-fragment order, split bf16 (hi,lo).
// B-operand layout (mfma_f32_16x16x32_bf16): lane l holds
// B[k = (l>>4)*8 + j][n = l&15]. Buffer: [kc(8)][ct(8)][p(hi/lo)][lane(64)][8]
// ct 0..3 -> Wq cols, ct 4..7 -> Wk. Wsp aliases the START of the pi output
// (written here, read by qk_mfma, overwritten later by attn -> stream-safe).
// ---------------------------------------------------------------------------
__global__ __launch_bounds__(64) void wprep_kernel(
    const float* __restrict__ Wq, const float* __restrict__ Wk,
    u16* __restrict__ Wsp)
{
    const int fid  = blockIdx.x;          // kc*8 + ct
    const int kc   = fid >> 3, ct = fid & 7;
    const int lane = threadIdx.x;
    const float* W = (ct < 4) ? Wq : Wk;
    const int col  = (ct & 3) * 16 + (lane & 15);
    const int krow = kc * 32 + (lane >> 4) * 8;
    bf16x8 hv, lv;
#pragma unroll
    for (int j = 0; j < 8; ++j) {
        float w = W[(size_t)(krow + j) * HH + col];
        float hf, d;
        hv[j] = bf_hi_bits(w, &hf);
        lv[j] = bf_hi_bits(w - hf, &d);
    }
    u16* dst = Wsp + (size_t)fid * 1024 + lane * 8;
    *(bf16x8*)dst         = hv;
    *(bf16x8*)(dst + 512) = lv;
}

// ---------------------------------------------------------------------------
// Kernel 1: Q/K projection, v3. One wave per block, 64 rows (4 x 16-row
// tiles) per wave. Rationale: Wsp (128 KB) is re-read by EVERY wave; rounds
// 2/4 had 1024-4096 waves -> 128 MB of L2/L3 traffic (~20+ us). 256 waves
// x 128 KB = 32 MB, L2-resident. acc = 4 tiles x 8 ct x f32x4 = 128 VGPR;
// 64-thread blocks tolerate ~210 VGPR peak without occupancy pressure.
// ---------------------------------------------------------------------------
__global__ __launch_bounds__(64) void qk_mfma_kernel(
    const float* __restrict__ f, const float* __restrict__ log_eps,
    const float* __restrict__ Wq, const float* __restrict__ Wk,
    const u16* __restrict__ Wsp,
    __hip_bfloat16* __restrict__ Qs, __hip_bfloat16* __restrict__ Ks)
{
    const int lane = threadIdx.x;
    const int l15  = lane & 15, quad = lane >> 4;
    const int row0 = blockIdx.x * 64;
    const int b    = row0 >> 11;          // 64-row blocks never straddle batch

    f32x4 acc[4][8] = {};
    const float* frow = f + (size_t)(row0 + l15) * DF + quad * 8;

#pragma unroll
    for (int kc = 0; kc < 8; ++kc) {
        bf16x8 ah[4], al[4];
#pragma unroll
        for (int t = 0; t < 4; ++t) {
            const float* fr = frow + ((size_t)t * 16) * DF + kc * 32;
            float4 a0 = *(const float4*)(fr);
            float4 a1 = *(const float4*)(fr + 4);
#pragma unroll
            for (int e = 0; e < 4; ++e) {
                float hf, d;
                float v0 = (&a0.x)[e], v1 = (&a1.x)[e];
                ah[t][e]     = bf_hi_bits(v0, &hf);
                al[t][e]     = bf_hi_bits(v0 - hf, &d);
                ah[t][e + 4] = bf_hi_bits(v1, &hf);
                al[t][e + 4] = bf_hi_bits(v1 - hf, &d);
            }
        }
        const u16* wb = Wsp + (size_t)kc * 8192 + lane * 8;
#pragma unroll
        for (int ct = 0; ct < 8; ++ct) {
            bf16x8 bh = *(const bf16x8*)(wb + ct * 1024);
            bf16x8 bl = *(const bf16x8*)(wb + ct * 1024 + 512);
#pragma unroll
            for (int t = 0; t < 4; ++t) {
                acc[t][ct] = __builtin_amdgcn_mfma_f32_16x16x32_bf16(ah[t], bh, acc[t][ct], 0, 0, 0);
                acc[t][ct] = __builtin_amdgcn_mfma_f32_16x16x32_bf16(ah[t], bl, acc[t][ct], 0, 0, 0);
                acc[t][ct] = __builtin_amdgcn_mfma_f32_16x16x32_bf16(al[t], bh, acc[t][ct], 0, 0, 0);
            }
        }
    }

    const float le = log_eps[b];
#pragma unroll
    for (int ct = 0; ct < 8; ++ct) {
        const int h = (ct & 3) * 16 + l15;
        const float wlast = (ct < 4 ? Wq : Wk)[DF * HH + h];
        __hip_bfloat16* out = (ct < 4) ? Qs : Ks;
        const float sc = (ct < 4) ? 0.125f : 1.0f;
#pragma unroll
        for (int t = 0; t < 4; ++t)
#pragma unroll
            for (int r = 0; r < 4; ++r) {
                int bn = row0 + t * 16 + quad * 4 + r;   // C/D: col=l15, row=quad*4+r
                float v = (acc[t][ct][r] + le * wlast) * sc;
                __hip_bfloat16 hi = __float2bfloat16(v);
                __hip_bfloat16 lo = __float2bfloat16(v - __bfloat162float(hi));
                out[(size_t)bn * 128 + h]      = hi;
                out[(size_t)bn * 128 + 64 + h] = lo;
            }
    }
}

// ---------------------------------------------------------------------------
// Kernel 2: fused attention, round-4 proven structure (64-col strips, 512
// threads, 2 passes, plain pi stores) plus:
//  - XCD-batch affinity: 1-D grid, b = bid & 7. HW round-robins workgroups
//    over the 8 XCDs, so batch i's 32 strips all land on XCD i; per-XCD
//    read set = Q_b + K_b + x_b ~ 1.3 MB << 4 MB L2. Round-4's (32,8) grid
//    spread all batches over every XCD (4 MB Qs + pi write streams -> L2
//    thrash -> Q re-reads served by L3 at ~6.4 TB/s; that was the wall).
//  - software-pipelined Q-fragment loads (static double buffer).
// ---------------------------------------------------------------------------
__global__ __launch_bounds__(512, 2) void attn_kernel(
    const u16* __restrict__ Qs, const u16* __restrict__ Ks,
    const float* __restrict__ x, float* __restrict__ y, float* __restrict__ pi)
{
    __shared__ float xs[NN * 3];             // 24 KB: x for this batch
    __shared__ float cred[64];               // strip colsums
    __shared__ float yred[8 * 4 * 16 * 3];   // [wave][ct][col16][d], 6 KB

    const int tid   = threadIdx.x;
    const int bid   = blockIdx.x;
    const int b     = bid & 7;               // XCD affinity
    const int strip = bid >> 3;              // 0..31
    const int m0    = strip * 64;
    const int wave  = tid >> 6;              // 0..7
    const int lane  = tid & 63;
    const int l15   = lane & 15;
    const int quad  = lane >> 4;

    if (tid < 64) cred[tid] = 0.f;
    for (int i = tid; i < NN * 3; i += 512) xs[i] = x[(size_t)b * NN * 3 + i];
    __syncthreads();

    // K-strip B-fragments (4 col-tiles), resident all kernel (~64 VGPR)
    bf16x8 bh[4][2], bl[4][2];
    {
        const u16* Kb = Ks + ((size_t)b * NN + m0) * 128;
#pragma unroll
        for (int ct = 0; ct < 4; ++ct) {
            const u16* kr = Kb + (size_t)(ct * 16 + l15) * 128;
#pragma unroll
            for (int ks = 0; ks < 2; ++ks) {
                int k0 = ks * 32 + quad * 8;
                bh[ct][ks] = *(const bf16x8*)(kr + k0);
                bl[ct][ks] = *(const bf16x8*)(kr + 64 + k0);
            }
        }
    }

    const u16* Qb = Qs + (size_t)b * NN * 128;

    // it in [0,16): row0 = (it>>1)*256 + wave*32 + (it&1)*16
#define ROWOF(it) ((((it) >> 1) << 8) + wave * 32 + (((it) & 1) << 4))

#define LOADQ(AH, AL, row0)                                                    \
    {                                                                          \
        const u16* qr = Qb + (size_t)((row0) + l15) * 128;                     \
        _Pragma("unroll")                                                      \
        for (int ks = 0; ks < 2; ++ks) {                                       \
            int k0 = ks * 32 + quad * 8;                                       \
            AH[ks] = *(const bf16x8*)(qr + k0);                                \
            AL[ks] = *(const bf16x8*)(qr + 64 + k0);                           \
        }                                                                      \
    }

#define QKMFMA(ACC, AH, AL, CT)                                                \
    {                                                                          \
        _Pragma("unroll")                                                      \
        for (int ks = 0; ks < 2; ++ks) {                                       \
            ACC = __builtin_amdgcn_mfma_f32_16x16x32_bf16(AH[ks], bh[CT][ks], ACC, 0, 0, 0); \
            ACC = __builtin_amdgcn_mfma_f32_16x16x32_bf16(AH[ks], bl[CT][ks], ACC, 0, 0, 0); \
            ACC = __builtin_amdgcn_mfma_f32_16x16x32_bf16(AL[ks], bh[CT][ks], ACC, 0, 0, 0); \
        }                                                                      \
    }

    float cs[4] = {0.f, 0.f, 0.f, 0.f};
    float yacc[4][3] = {};

    // ---- Pass 1: column sums + y accumulation, pipelined ----
#define P1BODY(it, AH, AL)                                                     \
    {                                                                          \
        const int row0 = ROWOF(it);                                            \
        float xv[4][3];                                                        \
        _Pragma("unroll")                                                      \
        for (int r = 0; r < 4; ++r) {                                          \
            int row = row0 + quad * 4 + r;                                     \
            xv[r][0] = xs[row * 3 + 0];                                        \
            xv[r][1] = xs[row * 3 + 1];                                        \
            xv[r][2] = xs[row * 3 + 2];                                        \
        }                                                                      \
        _Pragma("unroll")                                                      \
        for (int ct = 0; ct < 4; ++ct) {                                       \
            f32x4 acc = {0.f, 0.f, 0.f, 0.f};                                  \
            QKMFMA(acc, AH, AL, ct);                                           \
            float s = 0.f;                                                     \
            _Pragma("unroll")                                                  \
            for (int r = 0; r < 4; ++r) {                                      \
                float v = __expf(acc[r]);                                      \
                s += v;                                                        \
                yacc[ct][0] = fmaf(v, xv[r][0], yacc[ct][0]);                  \
                yacc[ct][1] = fmaf(v, xv[r][1], yacc[ct][1]);                  \
                yacc[ct][2] = fmaf(v, xv[r][2], yacc[ct][2]);                  \
            }                                                                  \
            cs[ct] += s;                                                       \
        }                                                                      \
    }

    {
        bf16x8 ahA[2], alA[2], ahB[2], alB[2];
        LOADQ(ahA, alA, ROWOF(0));
        for (int it = 0; it < 16; it += 2) {
            LOADQ(ahB, alB, ROWOF(it + 1));
            P1BODY(it, ahA, alA);
            if (it + 2 < 16) LOADQ(ahA, alA, ROWOF(it + 2));
            P1BODY(it + 1, ahB, alB);
        }
    }

    // deferred cross-quad reductions, then LDS
#pragma unroll
    for (int ct = 0; ct < 4; ++ct) {
        cs[ct] += __shfl_xor(cs[ct], 16);
        cs[ct] += __shfl_xor(cs[ct], 32);
#pragma unroll
        for (int d = 0; d < 3; ++d) {
            yacc[ct][d] += __shfl_xor(yacc[ct][d], 16);
            yacc[ct][d] += __shfl_xor(yacc[ct][d], 32);
        }
    }
    if (quad == 0) {
#pragma unroll
        for (int ct = 0; ct < 4; ++ct) {
            atomicAdd(&cred[ct * 16 + l15], cs[ct]);
#pragma unroll
            for (int d = 0; d < 3; ++d)
                yred[((wave * 4 + ct) * 16 + l15) * 3 + d] = yacc[ct][d];
        }
    }
    __syncthreads();

    if (tid < 192) {                         // 64 cols x 3 dims
        int c = tid / 3, d = tid - c * 3;
        int ct = c >> 4, cl = c & 15;
        float s = 0.f;
#pragma unroll
        for (int w = 0; w < 8; ++w)
            s += yred[((w * 4 + ct) * 16 + cl) * 3 + d];
        y[((size_t)b * NN + m0 + c) * 3 + d] = s / cred[c];
    }

    const float invN = 1.0f / (float)NN;
    float iv[4];
#pragma unroll
    for (int ct = 0; ct < 4; ++ct) iv[ct] = invN / cred[ct * 16 + l15];
    float* pib = pi + (size_t)b * NN * NN + m0;

    // ---- Pass 2: recompute, write pi (plain stores -> L2 coalesces) ----
#define P2BODY(it, AH, AL)                                                     \
    {                                                                          \
        const int row0 = ROWOF(it);                                            \
        _Pragma("unroll")                                                      \
        for (int ct = 0; ct < 4; ++ct) {                                       \
            f32x4 acc = {0.f, 0.f, 0.f, 0.f};                                  \
            QKMFMA(acc, AH, AL, ct);                                           \
            float* op = pib + (size_t)(row0 + quad * 4) * NN + ct * 16 + l15;  \
            _Pragma("unroll")                                                  \
            for (int r = 0; r < 4; ++r)                                        \
                op[(size_t)r * NN] = __expf(acc[r]) * iv[ct];                  \
        }                                                                      \
    }

    {
        bf16x8 ahA[2], alA[2], ahB[2], alB[2];
        LOADQ(ahA, alA, ROWOF(0));
        for (int it = 0; it < 16; it += 2) {
            LOADQ(ahB, alB, ROWOF(it + 1));
            P2BODY(it, ahA, alA);
            if (it + 2 < 16) LOADQ(ahA, alA, ROWOF(it + 2));
            P2BODY(it + 1, ahB, alB);
        }
    }
#undef ROWOF
#undef LOADQ
#undef QKMFMA
#undef P1BODY
#undef P2BODY
}

// ---------------------------------------------------------------------------
extern "C" void kernel_launch(void* const* d_in, const int* in_sizes, int n_in,
                              void* d_out, int out_size, void* d_ws, size_t ws_size,
                              hipStream_t stream) {
    const float* f  = (const float*)d_in[0];
    const float* x  = (const float*)d_in[1];
    const float* le = (const float*)d_in[2];
    const float* Wq = (const float*)d_in[3];
    const float* Wk = (const float*)d_in[4];

    float* y  = (float*)d_out;                       // (B, N, 3)
    float* pi = (float*)d_out + (size_t)BB * NN * 3; // (B, N, N)

    // Workspace: exactly the proven 8 MB (split-bf16 Q and K). The 128 KB
    // W-fragment table temporally aliases the pi output buffer.
    __hip_bfloat16* Qs = (__hip_bfloat16*)d_ws;      // 4 MB
    __hip_bfloat16* Ks = Qs + (size_t)BB * NN * 128; // 4 MB
    u16* Wsp = (u16*)pi;                             // 128 KB, stream-ordered alias

    wprep_kernel<<<dim3(64), 64, 0, stream>>>(Wq, Wk, Wsp);
    qk_mfma_kernel<<<dim3(BB * NN / 64), 64, 0, stream>>>(f, le, Wq, Wk, Wsp, Qs, Ks);
    attn_kernel<<<dim3(256), 512, 0, stream>>>((const u16*)Qs, (const u16*)Ks,
                                               x, y, pi);
}

// Round 7
// 194.283 us; speedup vs baseline: 1.0760x; 1.0760x over previous
//
#include <hip/hip_runtime.h>
#include <hip/hip_bf16.h>

// Dims fixed by the reference
#define BB 8
#define NN 2048
#define DF 256
#define HH 64

using bf16x8 = __attribute__((ext_vector_type(8))) short;
using f32x4  = __attribute__((ext_vector_type(4))) float;
typedef unsigned short u16;

static __device__ __forceinline__ short bf_hi_bits(float v, float* hi_f) {
    __hip_bfloat16 h = __float2bfloat16(v);
    *hi_f = __bfloat162float(h);
    return __builtin_bit_cast(short, h);
}

// ---------------------------------------------------------------------------
// Kernel 0: pre-split W (fp32) into MFMA B-fragment order, split bf16 (hi,lo).
// B-operand layout (mfma_f32_16x16x32_bf16): lane l holds
// B[k = (l>>4)*8 + j][n = l&15]. Buffer: [kc(8)][ct(8)][p(hi/lo)][lane(64)][8]
// ct 0..3 -> Wq cols, ct 4..7 -> Wk. Per (kc,ct): 1024 u16 (hi 512 | lo 512).
// Wsp aliases the START of the pi output (stream-ordered temporal alias).
// ---------------------------------------------------------------------------
__global__ __launch_bounds__(64) void wprep_kernel(
    const float* __restrict__ Wq, const float* __restrict__ Wk,
    u16* __restrict__ Wsp)
{
    const int fid  = blockIdx.x;          // kc*8 + ct
    const int kc   = fid >> 3, ct = fid & 7;
    const int lane = threadIdx.x;
    const float* W = (ct < 4) ? Wq : Wk;
    const int col  = (ct & 3) * 16 + (lane & 15);
    const int krow = kc * 32 + (lane >> 4) * 8;
    bf16x8 hv, lv;
#pragma unroll
    for (int j = 0; j < 8; ++j) {
        float w = W[(size_t)(krow + j) * HH + col];
        float hf, d;
        hv[j] = bf_hi_bits(w, &hf);
        lv[j] = bf_hi_bits(w - hf, &d);
    }
    u16* dst = Wsp + (size_t)fid * 1024 + lane * 8;
    *(bf16x8*)dst         = hv;
    *(bf16x8*)(dst + 512) = lv;
}

// ---------------------------------------------------------------------------
// Kernel 1: Q/K projection, v4 (fixed). Wsp staged in LDS once per BLOCK,
// shared by 4 waves: 256 blocks x 128 KB = 32 MB global traffic, staged as
// double-buffered 16 KB per-kc chunks. ROUND-6 BUG: LDS reads used ct*2048
// (+1024) instead of the layout's ct*1024 (+512) -> OOB garbage for ct>=4.
// Fixed here; structure otherwise identical.
// ---------------------------------------------------------------------------
__global__ __launch_bounds__(256) void qk_mfma_kernel(
    const float* __restrict__ f, const float* __restrict__ log_eps,
    const float* __restrict__ Wq, const float* __restrict__ Wk,
    const u16* __restrict__ Wsp,
    __hip_bfloat16* __restrict__ Qs, __hip_bfloat16* __restrict__ Ks)
{
    __shared__ __align__(16) u16 wbuf[2][8192];   // 2 x 16 KB kc-chunks

    const int tid  = threadIdx.x;
    const int wave = tid >> 6;
    const int lane = tid & 63;
    const int l15  = lane & 15, quad = lane >> 4;
    const int row0 = blockIdx.x * 64 + wave * 16; // this wave's 16-row tile
    const int b    = (blockIdx.x * 64) >> 11;     // blocks never straddle batch

    f32x4 acc[8] = {};
    const float* frow = f + (size_t)(row0 + l15) * DF + quad * 8;

    // stage kc=0 chunk (coalesced 4 x 16B per thread) + first f fragments
    {
        const uint4* src = (const uint4*)(Wsp + tid * 32);
        uint4* dst = (uint4*)&wbuf[0][tid * 32];
#pragma unroll
        for (int i = 0; i < 4; ++i) dst[i] = src[i];
    }
    float4 a0 = *(const float4*)(frow);
    float4 a1 = *(const float4*)(frow + 4);
    __syncthreads();

    for (int kc = 0; kc < 8; ++kc) {
        const int cur = kc & 1;
        uint4 w0, w1, w2, w3;                     // next W chunk (regs)
        float4 na0, na1;                          // next f fragments
        if (kc < 7) {
            const uint4* src =
                (const uint4*)(Wsp + (size_t)(kc + 1) * 8192 + tid * 32);
            w0 = src[0]; w1 = src[1]; w2 = src[2]; w3 = src[3];
            na0 = *(const float4*)(frow + (kc + 1) * 32);
            na1 = *(const float4*)(frow + (kc + 1) * 32 + 4);
        }
        // A-fragment: row = l15, k = quad*8 + j (fp32 -> split bf16)
        bf16x8 ah, al;
#pragma unroll
        for (int e = 0; e < 4; ++e) {
            float hf, d;
            float v0 = (&a0.x)[e], v1 = (&a1.x)[e];
            ah[e]     = bf_hi_bits(v0, &hf);
            al[e]     = bf_hi_bits(v0 - hf, &d);
            ah[e + 4] = bf_hi_bits(v1, &hf);
            al[e + 4] = bf_hi_bits(v1 - hf, &d);
        }
#pragma unroll
        for (int ct = 0; ct < 8; ++ct) {
            bf16x8 bh = *(const bf16x8*)&wbuf[cur][ct * 1024 + lane * 8];
            bf16x8 bl = *(const bf16x8*)&wbuf[cur][ct * 1024 + 512 + lane * 8];
            acc[ct] = __builtin_amdgcn_mfma_f32_16x16x32_bf16(ah, bh, acc[ct], 0, 0, 0);
            acc[ct] = __builtin_amdgcn_mfma_f32_16x16x32_bf16(ah, bl, acc[ct], 0, 0, 0);
            acc[ct] = __builtin_amdgcn_mfma_f32_16x16x32_bf16(al, bh, acc[ct], 0, 0, 0);
        }
        if (kc < 7) {
            uint4* dst = (uint4*)&wbuf[cur ^ 1][tid * 32];
            dst[0] = w0; dst[1] = w1; dst[2] = w2; dst[3] = w3;
            a0 = na0; a1 = na1;
        }
        __syncthreads();
    }

    const float le = log_eps[b];
#pragma unroll
    for (int ct = 0; ct < 8; ++ct) {
        const int h = (ct & 3) * 16 + l15;
        const float wlast = (ct < 4 ? Wq : Wk)[DF * HH + h];
        __hip_bfloat16* out = (ct < 4) ? Qs : Ks;
        const float sc = (ct < 4) ? 0.125f : 1.0f;
#pragma unroll
        for (int r = 0; r < 4; ++r) {
            int bn = row0 + quad * 4 + r;         // C/D: col=l15, row=quad*4+r
            float v = (acc[ct][r] + le * wlast) * sc;
            __hip_bfloat16 hi = __float2bfloat16(v);
            __hip_bfloat16 lo = __float2bfloat16(v - __bfloat162float(hi));
            out[(size_t)bn * 128 + h]      = hi;
            out[(size_t)bn * 128 + 64 + h] = lo;
        }
    }
}

// ---------------------------------------------------------------------------
// Kernel 2: fused attention — BYTE-IDENTICAL to round 4 (64-col strips, 512
// threads, 2 passes, plain pi stores, grid (32,8)). Unchanged so that
// r7_total - r4_total attributes the qk_v4 delta exactly.
// ---------------------------------------------------------------------------
__global__ __launch_bounds__(512, 2) void attn_kernel(
    const u16* __restrict__ Qs, const u16* __restrict__ Ks,
    const float* __restrict__ x, float* __restrict__ y, float* __restrict__ pi)
{
    __shared__ float xs[NN * 3];             // 24 KB: x for this batch
    __shared__ float cred[64];               // strip colsums
    __shared__ float yred[8 * 4 * 16 * 3];   // [wave][ct][col16][d], 6 KB

    const int tid   = threadIdx.x;
    const int strip = blockIdx.x;            // 0..31
    const int b     = blockIdx.y;            // 0..7
    const int m0    = strip * 64;
    const int wave  = tid >> 6;              // 0..7
    const int lane  = tid & 63;
    const int l15   = lane & 15;
    const int quad  = lane >> 4;

    if (tid < 64) cred[tid] = 0.f;
    for (int i = tid; i < NN * 3; i += 512) xs[i] = x[(size_t)b * NN * 3 + i];
    __syncthreads();

    // K-strip B-fragments (4 col-tiles), resident all kernel (~64 VGPR)
    bf16x8 bh[4][2], bl[4][2];
    {
        const u16* Kb = Ks + ((size_t)b * NN + m0) * 128;
#pragma unroll
        for (int ct = 0; ct < 4; ++ct) {
            const u16* kr = Kb + (size_t)(ct * 16 + l15) * 128;
#pragma unroll
            for (int ks = 0; ks < 2; ++ks) {
                int k0 = ks * 32 + quad * 8;
                bh[ct][ks] = *(const bf16x8*)(kr + k0);
                bl[ct][ks] = *(const bf16x8*)(kr + 64 + k0);
            }
        }
    }

    const u16* Qb = Qs + (size_t)b * NN * 128;
    float cs[4] = {0.f, 0.f, 0.f, 0.f};
    float yacc[4][3] = {};

    // ---- Pass 1: column sums + y accumulation ----
    for (int rt = 0; rt < 8; ++rt) {
#pragma unroll
        for (int sr = 0; sr < 2; ++sr) {
            const int row0 = rt * 256 + wave * 32 + sr * 16;
            const u16* qr = Qb + (size_t)(row0 + l15) * 128;
            bf16x8 ah[2], al[2];
#pragma unroll
            for (int ks = 0; ks < 2; ++ks) {
                int k0 = ks * 32 + quad * 8;
                ah[ks] = *(const bf16x8*)(qr + k0);
                al[ks] = *(const bf16x8*)(qr + 64 + k0);
            }
            float xv[4][3];
#pragma unroll
            for (int r = 0; r < 4; ++r) {
                int row = row0 + quad * 4 + r;
                xv[r][0] = xs[row * 3 + 0];
                xv[r][1] = xs[row * 3 + 1];
                xv[r][2] = xs[row * 3 + 2];
            }
#pragma unroll
            for (int ct = 0; ct < 4; ++ct) {
                f32x4 acc = {0.f, 0.f, 0.f, 0.f};
#pragma unroll
                for (int ks = 0; ks < 2; ++ks) {
                    acc = __builtin_amdgcn_mfma_f32_16x16x32_bf16(ah[ks], bh[ct][ks], acc, 0, 0, 0);
                    acc = __builtin_amdgcn_mfma_f32_16x16x32_bf16(ah[ks], bl[ct][ks], acc, 0, 0, 0);
                    acc = __builtin_amdgcn_mfma_f32_16x16x32_bf16(al[ks], bh[ct][ks], acc, 0, 0, 0);
                }
                float s = 0.f;
#pragma unroll
                for (int r = 0; r < 4; ++r) {
                    float v = __expf(acc[r]);
                    s += v;
                    yacc[ct][0] = fmaf(v, xv[r][0], yacc[ct][0]);
                    yacc[ct][1] = fmaf(v, xv[r][1], yacc[ct][1]);
                    yacc[ct][2] = fmaf(v, xv[r][2], yacc[ct][2]);
                }
                cs[ct] += s;
            }
        }
    }

    // deferred cross-quad reductions, then LDS
#pragma unroll
    for (int ct = 0; ct < 4; ++ct) {
        cs[ct] += __shfl_xor(cs[ct], 16);
        cs[ct] += __shfl_xor(cs[ct], 32);
#pragma unroll
        for (int d = 0; d < 3; ++d) {
            yacc[ct][d] += __shfl_xor(yacc[ct][d], 16);
            yacc[ct][d] += __shfl_xor(yacc[ct][d], 32);
        }
    }
    if (quad == 0) {
#pragma unroll
        for (int ct = 0; ct < 4; ++ct) {
            atomicAdd(&cred[ct * 16 + l15], cs[ct]);
#pragma unroll
            for (int d = 0; d < 3; ++d)
                yred[((wave * 4 + ct) * 16 + l15) * 3 + d] = yacc[ct][d];
        }
    }
    __syncthreads();

    if (tid < 192) {                         // 64 cols x 3 dims
        int c = tid / 3, d = tid - c * 3;
        int ct = c >> 4, cl = c & 15;
        float s = 0.f;
#pragma unroll
        for (int w = 0; w < 8; ++w)
            s += yred[((w * 4 + ct) * 16 + cl) * 3 + d];
        y[((size_t)b * NN + m0 + c) * 3 + d] = s / cred[c];
    }

    const float invN = 1.0f / (float)NN;
    float iv[4];
#pragma unroll
    for (int ct = 0; ct < 4; ++ct) iv[ct] = invN / cred[ct * 16 + l15];
    float* pib = pi + (size_t)b * NN * NN + m0;

    // ---- Pass 2: recompute, write pi (plain stores -> L2 coalesces) ----
    for (int rt = 0; rt < 8; ++rt) {
#pragma unroll
        for (int sr = 0; sr < 2; ++sr) {
            const int row0 = rt * 256 + wave * 32 + sr * 16;
            const u16* qr = Qb + (size_t)(row0 + l15) * 128;
            bf16x8 ah[2], al[2];
#pragma unroll
            for (int ks = 0; ks < 2; ++ks) {
                int k0 = ks * 32 + quad * 8;
                ah[ks] = *(const bf16x8*)(qr + k0);
                al[ks] = *(const bf16x8*)(qr + 64 + k0);
            }
#pragma unroll
            for (int ct = 0; ct < 4; ++ct) {
                f32x4 acc = {0.f, 0.f, 0.f, 0.f};
#pragma unroll
                for (int ks = 0; ks < 2; ++ks) {
                    acc = __builtin_amdgcn_mfma_f32_16x16x32_bf16(ah[ks], bh[ct][ks], acc, 0, 0, 0);
                    acc = __builtin_amdgcn_mfma_f32_16x16x32_bf16(ah[ks], bl[ct][ks], acc, 0, 0, 0);
                    acc = __builtin_amdgcn_mfma_f32_16x16x32_bf16(al[ks], bh[ct][ks], acc, 0, 0, 0);
                }
                float* op = pib + (size_t)(row0 + quad * 4) * NN + ct * 16 + l15;
#pragma unroll
                for (int r = 0; r < 4; ++r)
                    op[(size_t)r * NN] = __expf(acc[r]) * iv[ct];
            }
        }
    }
}

// ---------------------------------------------------------------------------
extern "C" void kernel_launch(void* const* d_in, const int* in_sizes, int n_in,
                              void* d_out, int out_size, void* d_ws, size_t ws_size,
                              hipStream_t stream) {
    const float* f  = (const float*)d_in[0];
    const float* x  = (const float*)d_in[1];
    const float* le = (const float*)d_in[2];
    const float* Wq = (const float*)d_in[3];
    const float* Wk = (const float*)d_in[4];

    float* y  = (float*)d_out;                       // (B, N, 3)
    float* pi = (float*)d_out + (size_t)BB * NN * 3; // (B, N, N)

    // Workspace: exactly the proven 8 MB (split-bf16 Q and K). The 128 KB
    // W-fragment table temporally aliases the pi output buffer.
    __hip_bfloat16* Qs = (__hip_bfloat16*)d_ws;      // 4 MB
    __hip_bfloat16* Ks = Qs + (size_t)BB * NN * 128; // 4 MB
    u16* Wsp = (u16*)pi;                             // 128 KB, stream-ordered alias

    wprep_kernel<<<dim3(64), 64, 0, stream>>>(Wq, Wk, Wsp);
    qk_mfma_kernel<<<dim3(BB * NN / 64), 256, 0, stream>>>(f, le, Wq, Wk, Wsp, Qs, Ks);
    attn_kernel<<<dim3(32, BB), 512, 0, stream>>>((const u16*)Qs, (const u16*)Ks,
                                                  x, y, pi);
}